// Round 1
// baseline (3136.590 us; speedup 1.0000x reference)
//
#include <hip/hip_runtime.h>

static inline int idiv_up(long a, long b) { return (int)((a + b - 1) / b); }

// ---------------------------------------------------------------------------
// Kernel 0: fold weights.
//   Wcomb[f][j] = sum_c W_emb[f][c] * Wcat[c][j]      (f<32, j<320)
//   bcomb[j]    = sum_c b_emb[c]    * Wcat[c][j]
// column map j: [0,128) = Q (h=j>>5, k=j&31), [128,256) = K, [256,320) = V0
// ---------------------------------------------------------------------------
__global__ __launch_bounds__(256) void fold_weights(
    const float* __restrict__ W_emb, const float* __restrict__ b_emb,
    const float* __restrict__ Wq, const float* __restrict__ Wk,
    const float* __restrict__ Wv0,
    float* __restrict__ Wcomb, float* __restrict__ bcomb)
{
    int idx = blockIdx.x * 256 + threadIdx.x;
    if (idx >= 33 * 320) return;
    int row = idx / 320, j = idx - row * 320;
    float acc = 0.f;
    for (int c = 0; c < 64; ++c) {
        float w;
        if (j < 128)      { int h = j >> 5,        k = j & 31;        w = Wq [(h * 64 + c) * 32 + k]; }
        else if (j < 256) { int h = (j - 128) >> 5, k = (j - 128) & 31; w = Wk [(h * 64 + c) * 32 + k]; }
        else              { int h = (j - 256) >> 4, v = (j - 256) & 15; w = Wv0[(h * 64 + c) * 16 + v]; }
        float lhs = (row < 32) ? W_emb[row * 64 + c] : b_emb[c];
        acc += lhs * w;
    }
    if (row < 32) Wcomb[row * 320 + j] = acc;
    else          bcomb[j] = acc;
}

// ---------------------------------------------------------------------------
// Kernel 1: per-node QKV tables. QKV[n][0:128]=Q(h,k) [128:256]=K(h,k) [256:320]=V0(h,v)
// block handles 256 nodes for ONE column-chunk c (32 cols) -> uniform LDS reads
// ---------------------------------------------------------------------------
__global__ __launch_bounds__(256) void node_qkv(
    const float* __restrict__ nf, const float* __restrict__ Wcomb,
    const float* __restrict__ bcomb, float* __restrict__ QKV, int Nn)
{
    int c    = blockIdx.x % 10;
    int tile = blockIdx.x / 10;
    __shared__ float sW[32][32];
    __shared__ float sb[32];
    for (int i = threadIdx.x; i < 1024; i += 256) {
        int f = i >> 5, j = i & 31;
        sW[f][j] = Wcomb[f * 320 + c * 32 + j];
    }
    if (threadIdx.x < 32) sb[threadIdx.x] = bcomb[c * 32 + threadIdx.x];
    __syncthreads();
    int n = tile * 256 + threadIdx.x;
    if (n >= Nn) return;

    float nfv[32];
    const float4* nfp = (const float4*)(nf + (size_t)n * 32);
#pragma unroll
    for (int f4 = 0; f4 < 8; ++f4) {
        float4 v = nfp[f4];
        nfv[f4 * 4 + 0] = v.x; nfv[f4 * 4 + 1] = v.y;
        nfv[f4 * 4 + 2] = v.z; nfv[f4 * 4 + 3] = v.w;
    }
    float acc[32];
#pragma unroll
    for (int j = 0; j < 32; ++j) acc[j] = sb[j];
#pragma unroll
    for (int f = 0; f < 32; ++f) {
        float x = nfv[f];
#pragma unroll
        for (int j4 = 0; j4 < 8; ++j4) {
            float4 w = *(const float4*)&sW[f][j4 * 4];
            acc[j4 * 4 + 0] += x * w.x; acc[j4 * 4 + 1] += x * w.y;
            acc[j4 * 4 + 2] += x * w.z; acc[j4 * 4 + 3] += x * w.w;
        }
    }
    float4* outp = (float4*)(QKV + (size_t)n * 320 + c * 32);
#pragma unroll
    for (int j4 = 0; j4 < 8; ++j4) {
        float4 v;
        v.x = acc[j4 * 4 + 0]; v.y = acc[j4 * 4 + 1];
        v.z = acc[j4 * 4 + 2]; v.w = acc[j4 * 4 + 3];
        outp[j4] = v;
    }
}

// ordered-uint encoding for float atomic max
__device__ __forceinline__ unsigned enc_f32(float f) {
    unsigned b = __float_as_uint(f);
    return (b & 0x80000000u) ? ~b : (b | 0x80000000u);
}
__device__ __forceinline__ float dec_f32(unsigned u) {
    return (u & 0x80000000u) ? __uint_as_float(u & 0x7FFFFFFFu) : __uint_as_float(~u);
}

// ---------------------------------------------------------------------------
// Kernel 2: per-edge scores + atomic segment max.
//   d = ||pos[dst]-pos[src]|| + 1e-8
//   rh[h,r] = silu(d*R1[h,r] + b1[h,r])
//   rk[h,k] = b2[h,k] + sum_r rh*R2[h,r,k]          (k < DK)
//   score[h] = sum_k Q[dst,h,k]*K[src,h,k]*rk[h,k] / sqrt(DK)
// ---------------------------------------------------------------------------
__global__ __launch_bounds__(256) void edge_scores(
    const float* __restrict__ pos, const int* __restrict__ ei,
    const float* __restrict__ QKV,
    const float* __restrict__ R1, const float* __restrict__ b1,
    const float* __restrict__ R2, const float* __restrict__ b2,
    float* __restrict__ scores, unsigned* __restrict__ m_enc, int Ee)
{
    __shared__ float sR2[4][16][32];   // k<32 columns of R2
    __shared__ float sR1[64], sb1[64];
    __shared__ float sb2k[4][32];
    for (int i = threadIdx.x; i < 2048; i += 256) {
        int h = i >> 9, rem = i & 511, r = rem >> 5, k = rem & 31;
        sR2[h][r][k] = R2[(h * 16 + r) * 64 + k];
    }
    for (int i = threadIdx.x; i < 64; i += 256) { sR1[i] = R1[i]; sb1[i] = b1[i]; }
    for (int i = threadIdx.x; i < 128; i += 256) {
        int h = i >> 5, k = i & 31;
        sb2k[h][k] = b2[h * 64 + k];
    }
    __syncthreads();

    int e = blockIdx.x * 256 + threadIdx.x;
    if (e >= Ee) return;
    int s  = ei[e];
    int dg = ei[Ee + e];
    float dx = pos[(size_t)dg * 3 + 0] - pos[(size_t)s * 3 + 0];
    float dy = pos[(size_t)dg * 3 + 1] - pos[(size_t)s * 3 + 1];
    float dz = pos[(size_t)dg * 3 + 2] - pos[(size_t)s * 3 + 2];
    float d = sqrtf(dx * dx + dy * dy + dz * dz) + 1e-8f;
    const float rs = 0.17677669529663687f; // 1/sqrt(32)

    float4 sc4;
    float* scp = (float*)&sc4;
#pragma unroll
    for (int h = 0; h < 4; ++h) {
        float rh[16];
#pragma unroll
        for (int r = 0; r < 16; ++r) {
            float x = d * sR1[h * 16 + r] + sb1[h * 16 + r];
            rh[r] = x / (1.f + __expf(-x));
        }
        const float4* Qd = (const float4*)(QKV + (size_t)dg * 320 + h * 32);
        const float4* Ks = (const float4*)(QKV + (size_t)s  * 320 + 128 + h * 32);
        float acc = 0.f;
#pragma unroll
        for (int k4 = 0; k4 < 8; ++k4) {
            float4 rkv = *(const float4*)&sb2k[h][k4 * 4];
#pragma unroll
            for (int r = 0; r < 16; ++r) {
                float4 w = *(const float4*)&sR2[h][r][k4 * 4];
                rkv.x += rh[r] * w.x; rkv.y += rh[r] * w.y;
                rkv.z += rh[r] * w.z; rkv.w += rh[r] * w.w;
            }
            float4 qv = Qd[k4], kv = Ks[k4];
            acc += qv.x * kv.x * rkv.x + qv.y * kv.y * rkv.y
                 + qv.z * kv.z * rkv.z + qv.w * kv.w * rkv.w;
        }
        float sv = acc * rs;
        scp[h] = sv;
        atomicMax(&m_enc[(size_t)dg * 4 + h], enc_f32(sv));
    }
    *(float4*)(scores + (size_t)e * 4) = sc4;
}

// ---------------------------------------------------------------------------
// Kernel 3: per-edge exp + atomic accumulation of denom and numerators.
//   rv0[h,v] = b2[h,32+v] + sum_r rh*R2[h,r,32+v]
//   ex = exp(score - m[dst]); denom[dst,h] += ex; num[dst,h,v] += ex*V0[src,h,v]*rv0
// ---------------------------------------------------------------------------
__global__ __launch_bounds__(256) void edge_accum(
    const float* __restrict__ pos, const int* __restrict__ ei,
    const float* __restrict__ QKV,
    const float* __restrict__ R1, const float* __restrict__ b1,
    const float* __restrict__ R2, const float* __restrict__ b2,
    const float* __restrict__ scores, const unsigned* __restrict__ m_enc,
    float* __restrict__ denom, float* __restrict__ num, int Ee)
{
    __shared__ float sR2[4][16][16];   // columns 32..48 of R2
    __shared__ float sR1[64], sb1[64];
    __shared__ float sb2v[4][16];
    for (int i = threadIdx.x; i < 1024; i += 256) {
        int h = i >> 8, rem = i & 255, r = rem >> 4, v = rem & 15;
        sR2[h][r][v] = R2[(h * 16 + r) * 64 + 32 + v];
    }
    for (int i = threadIdx.x; i < 64; i += 256) { sR1[i] = R1[i]; sb1[i] = b1[i]; }
    if (threadIdx.x < 64) {
        int h = threadIdx.x >> 4, v = threadIdx.x & 15;
        sb2v[h][v] = b2[h * 64 + 32 + v];
    }
    __syncthreads();

    int e = blockIdx.x * 256 + threadIdx.x;
    if (e >= Ee) return;
    int s  = ei[e];
    int dg = ei[Ee + e];
    float dx = pos[(size_t)dg * 3 + 0] - pos[(size_t)s * 3 + 0];
    float dy = pos[(size_t)dg * 3 + 1] - pos[(size_t)s * 3 + 1];
    float dz = pos[(size_t)dg * 3 + 2] - pos[(size_t)s * 3 + 2];
    float d = sqrtf(dx * dx + dy * dy + dz * dz) + 1e-8f;

    float4 sc4 = *(const float4*)(scores + (size_t)e * 4);
    const float* scp = (const float*)&sc4;

#pragma unroll
    for (int h = 0; h < 4; ++h) {
        float rh[16];
#pragma unroll
        for (int r = 0; r < 16; ++r) {
            float x = d * sR1[h * 16 + r] + sb1[h * 16 + r];
            rh[r] = x / (1.f + __expf(-x));
        }
        float rv[16];
#pragma unroll
        for (int v4 = 0; v4 < 4; ++v4) {
            float4 a = *(const float4*)&sb2v[h][v4 * 4];
#pragma unroll
            for (int r = 0; r < 16; ++r) {
                float4 w = *(const float4*)&sR2[h][r][v4 * 4];
                a.x += rh[r] * w.x; a.y += rh[r] * w.y;
                a.z += rh[r] * w.z; a.w += rh[r] * w.w;
            }
            rv[v4 * 4 + 0] = a.x; rv[v4 * 4 + 1] = a.y;
            rv[v4 * 4 + 2] = a.z; rv[v4 * 4 + 3] = a.w;
        }
        float m  = dec_f32(m_enc[(size_t)dg * 4 + h]);
        float ex = __expf(scp[h] - m);
        atomicAdd(&denom[(size_t)dg * 4 + h], ex);
        const float4* V = (const float4*)(QKV + (size_t)s * 320 + 256 + h * 16);
        float* np = num + ((size_t)dg * 4 + h) * 16;
#pragma unroll
        for (int v4 = 0; v4 < 4; ++v4) {
            float4 vv = V[v4];
            atomicAdd(&np[v4 * 4 + 0], ex * vv.x * rv[v4 * 4 + 0]);
            atomicAdd(&np[v4 * 4 + 1], ex * vv.y * rv[v4 * 4 + 1]);
            atomicAdd(&np[v4 * 4 + 2], ex * vv.z * rv[v4 * 4 + 2]);
            atomicAdd(&np[v4 * 4 + 3], ex * vv.w * rv[v4 * 4 + 3]);
        }
    }
}

// ---------------------------------------------------------------------------
// Kernel 4: per-node divide + pool over batch.
// ---------------------------------------------------------------------------
__global__ __launch_bounds__(256) void node_pool(
    const float* __restrict__ denom, const float* __restrict__ num,
    const int* __restrict__ batch, float* __restrict__ pooled, long total)
{
    long idx = (long)blockIdx.x * 256 + threadIdx.x;
    if (idx >= total) return;
    long n = idx >> 6;
    int  i = (int)(idx & 63);
    int  h = i >> 4;
    float dn = denom[n * 4 + h] + 1e-9f;
    float o  = num[n * 64 + i] / dn;
    atomicAdd(&pooled[(size_t)batch[n] * 64 + i], o);
}

// ---------------------------------------------------------------------------
// Kernel 5: out[b][o] = sum_i pooled[b][i] * Wproj[i][o]
// ---------------------------------------------------------------------------
__global__ __launch_bounds__(256) void final_proj(
    const float* __restrict__ pooled, const float* __restrict__ Wproj,
    float* __restrict__ out, int total)
{
    int idx = blockIdx.x * 256 + threadIdx.x;
    if (idx >= total) return;
    int b = idx >> 6, o = idx & 63;
    float acc = 0.f;
#pragma unroll
    for (int i = 0; i < 64; ++i) acc += pooled[b * 64 + i] * Wproj[i * 64 + o];
    out[idx] = acc;
}

extern "C" void kernel_launch(void* const* d_in, const int* in_sizes, int n_in,
                              void* d_out, int out_size, void* d_ws, size_t ws_size,
                              hipStream_t stream)
{
    const float* pos   = (const float*)d_in[0];
    const float* nf    = (const float*)d_in[1];
    const int*   ei    = (const int*)d_in[2];
    const int*   batch = (const int*)d_in[3];
    const float* W_emb = (const float*)d_in[4];
    const float* b_emb = (const float*)d_in[5];
    const float* Wq    = (const float*)d_in[6];
    const float* Wk    = (const float*)d_in[7];
    const float* Wv0   = (const float*)d_in[8];
    const float* R1    = (const float*)d_in[10];
    const float* b1    = (const float*)d_in[11];
    const float* R2    = (const float*)d_in[12];
    const float* b2    = (const float*)d_in[13];
    const float* Wproj = (const float*)d_in[14];
    float* out = (float*)d_out;

    long Nn = in_sizes[0] / 3;
    long Ee = in_sizes[2] / 2;
    int  Bb = out_size / 64;

    float* ws = (float*)d_ws;
    size_t WCOMB = 0;
    size_t BCOMB = WCOMB + 32 * 320;
    size_t QKV_O = BCOMB + 320;                  // 10560
    size_t SCORE = QKV_O + (size_t)Nn * 320;
    size_t MENC  = SCORE + (size_t)Ee * 4;
    size_t DEN   = MENC + (size_t)Nn * 4;
    size_t NUM   = DEN + (size_t)Nn * 4;
    size_t POOL  = NUM + (size_t)Nn * 64;
    size_t END   = POOL + (size_t)Bb * 64;

    // zero the accumulator region (m_enc .. pooled, contiguous)
    hipMemsetAsync(ws + MENC, 0, (END - MENC) * sizeof(float), stream);

    fold_weights<<<idiv_up(33 * 320, 256), 256, 0, stream>>>(
        W_emb, b_emb, Wq, Wk, Wv0, ws + WCOMB, ws + BCOMB);

    node_qkv<<<idiv_up(Nn, 256) * 10, 256, 0, stream>>>(
        nf, ws + WCOMB, ws + BCOMB, ws + QKV_O, (int)Nn);

    edge_scores<<<idiv_up(Ee, 256), 256, 0, stream>>>(
        pos, ei, ws + QKV_O, R1, b1, R2, b2,
        ws + SCORE, (unsigned*)(ws + MENC), (int)Ee);

    edge_accum<<<idiv_up(Ee, 256), 256, 0, stream>>>(
        pos, ei, ws + QKV_O, R1, b1, R2, b2,
        ws + SCORE, (const unsigned*)(ws + MENC),
        ws + DEN, ws + NUM, (int)Ee);

    node_pool<<<idiv_up(Nn * 64, 256), 256, 0, stream>>>(
        ws + DEN, ws + NUM, batch, ws + POOL, Nn * 64);

    final_proj<<<idiv_up(out_size, 256), 256, 0, stream>>>(
        ws + POOL, Wproj, out, out_size);
}

// Round 2
// 494.450 us; speedup vs baseline: 6.3436x; 6.3436x over previous
//
#include <hip/hip_runtime.h>

static inline int idiv_up(long a, long b) { return (int)((a + b - 1) / b); }

// ---------------------------------------------------------------------------
// Kernel 0: fold weights.  Wcomb[f][j] = sum_c W_emb[f][c]*Wcat[c][j]
// column map j: [0,128)=Q (h=j>>5,k=j&31), [128,256)=K, [256,320)=V0
// ---------------------------------------------------------------------------
__global__ __launch_bounds__(256) void fold_weights(
    const float* __restrict__ W_emb, const float* __restrict__ b_emb,
    const float* __restrict__ Wq, const float* __restrict__ Wk,
    const float* __restrict__ Wv0,
    float* __restrict__ Wcomb, float* __restrict__ bcomb)
{
    int idx = blockIdx.x * 256 + threadIdx.x;
    if (idx >= 33 * 320) return;
    int row = idx / 320, j = idx - row * 320;
    float acc = 0.f;
    for (int c = 0; c < 64; ++c) {
        float w;
        if (j < 128)      { int h = j >> 5,         k = j & 31;         w = Wq [(h * 64 + c) * 32 + k]; }
        else if (j < 256) { int h = (j - 128) >> 5, k = (j - 128) & 31; w = Wk [(h * 64 + c) * 32 + k]; }
        else              { int h = (j - 256) >> 4, v = (j - 256) & 15; w = Wv0[(h * 64 + c) * 16 + v]; }
        float lhs = (row < 32) ? W_emb[row * 64 + c] : b_emb[c];
        acc += lhs * w;
    }
    if (row < 32) Wcomb[row * 320 + j] = acc;
    else          bcomb[j] = acc;
}

// ---------------------------------------------------------------------------
// Kernel 1: per-node QKV tables. QKV[n][0:128]=Q [128:256]=K [256:320]=V0
// ---------------------------------------------------------------------------
__global__ __launch_bounds__(256) void node_qkv(
    const float* __restrict__ nf, const float* __restrict__ Wcomb,
    const float* __restrict__ bcomb, float* __restrict__ QKV, int Nn)
{
    int c    = blockIdx.x % 10;
    int tile = blockIdx.x / 10;
    __shared__ float sW[32][32];
    __shared__ float sb[32];
    for (int i = threadIdx.x; i < 1024; i += 256) {
        int f = i >> 5, j = i & 31;
        sW[f][j] = Wcomb[f * 320 + c * 32 + j];
    }
    if (threadIdx.x < 32) sb[threadIdx.x] = bcomb[c * 32 + threadIdx.x];
    __syncthreads();
    int n = tile * 256 + threadIdx.x;
    if (n >= Nn) return;

    float nfv[32];
    const float4* nfp = (const float4*)(nf + (size_t)n * 32);
#pragma unroll
    for (int f4 = 0; f4 < 8; ++f4) {
        float4 v = nfp[f4];
        nfv[f4 * 4 + 0] = v.x; nfv[f4 * 4 + 1] = v.y;
        nfv[f4 * 4 + 2] = v.z; nfv[f4 * 4 + 3] = v.w;
    }
    float acc[32];
#pragma unroll
    for (int j = 0; j < 32; ++j) acc[j] = sb[j];
#pragma unroll
    for (int f = 0; f < 32; ++f) {
        float x = nfv[f];
#pragma unroll
        for (int j4 = 0; j4 < 8; ++j4) {
            float4 w = *(const float4*)&sW[f][j4 * 4];
            acc[j4 * 4 + 0] += x * w.x; acc[j4 * 4 + 1] += x * w.y;
            acc[j4 * 4 + 2] += x * w.z; acc[j4 * 4 + 3] += x * w.w;
        }
    }
    float4* outp = (float4*)(QKV + (size_t)n * 320 + c * 32);
#pragma unroll
    for (int j4 = 0; j4 < 8; ++j4) {
        float4 v;
        v.x = acc[j4 * 4 + 0]; v.y = acc[j4 * 4 + 1];
        v.z = acc[j4 * 4 + 2]; v.w = acc[j4 * 4 + 3];
        outp[j4] = v;
    }
}

// ---------------------------------------------------------------------------
// Kernel 2: degree count (1 int atomic per edge)
// ---------------------------------------------------------------------------
__global__ __launch_bounds__(256) void count_deg(
    const int* __restrict__ ei, int* __restrict__ deg, int Ee)
{
    int e = blockIdx.x * 256 + threadIdx.x;
    if (e >= Ee) return;
    atomicAdd(&deg[ei[Ee + e]], 1);
}

// ---------------------------------------------------------------------------
// Kernel 3: exclusive scan of deg -> offs, cursor (single block, 1024 thr)
// ---------------------------------------------------------------------------
__global__ __launch_bounds__(1024) void scan_deg(
    const int* __restrict__ deg, int* __restrict__ offs,
    int* __restrict__ cursor, int Nn)
{
    __shared__ int part[1024];
    int chunk = (Nn + 1023) / 1024;
    int start = threadIdx.x * chunk;
    int end   = min(start + chunk, Nn);
    int s = 0;
    for (int i = start; i < end; ++i) s += deg[i];
    part[threadIdx.x] = s;
    __syncthreads();
    for (int off = 1; off < 1024; off <<= 1) {
        int v = 0;
        if ((int)threadIdx.x >= off) v = part[threadIdx.x - off];
        __syncthreads();
        if ((int)threadIdx.x >= off) part[threadIdx.x] += v;
        __syncthreads();
    }
    int excl = (threadIdx.x == 0) ? 0 : part[threadIdx.x - 1];
    for (int i = start; i < end; ++i) {
        offs[i] = excl; cursor[i] = excl;
        excl += deg[i];
    }
}

// ---------------------------------------------------------------------------
// Kernel 4: scatter edges into CSR-by-dst; precompute d.
// ---------------------------------------------------------------------------
__global__ __launch_bounds__(256) void scatter_edges(
    const float* __restrict__ pos, const int* __restrict__ ei,
    int* __restrict__ cursor, int* __restrict__ csr_src,
    float* __restrict__ csr_d, int Ee)
{
    int e = blockIdx.x * 256 + threadIdx.x;
    if (e >= Ee) return;
    int s  = ei[e];
    int dg = ei[Ee + e];
    float dx = pos[(size_t)dg * 3 + 0] - pos[(size_t)s * 3 + 0];
    float dy = pos[(size_t)dg * 3 + 1] - pos[(size_t)s * 3 + 1];
    float dz = pos[(size_t)dg * 3 + 2] - pos[(size_t)s * 3 + 2];
    float d = sqrtf(dx * dx + dy * dy + dz * dz) + 1e-8f;
    int p = atomicAdd(&cursor[dg], 1);
    csr_src[p] = s;
    csr_d[p] = d;
}

// ---------------------------------------------------------------------------
// Kernel 5: fused per-node attention (wave per node, grid-stride).
// Lane layout: h = lane>>4, j = lane&15.
//   per edge: rh[h][r] = silu(d*R1+b1) at lane (h,r); broadcast via shfl;
//   rk(2 cols) + rv(1 col) matvec with R2 columns held in registers;
//   score = sum_k Q[n]K[src]rk /sqrt(32) reduced via shfl_xor within group;
//   online softmax: running m,l, acc (lane holds num[h][j]).
// Output folded directly into batch-pooled table (64 atomics / node).
// ---------------------------------------------------------------------------
__global__ __launch_bounds__(256) void node_attn(
    const float* __restrict__ QKV, const int* __restrict__ csr_src,
    const float* __restrict__ csr_d, const int* __restrict__ offs,
    const int* __restrict__ deg, const int* __restrict__ batch,
    const float* __restrict__ R1, const float* __restrict__ b1,
    const float* __restrict__ R2, const float* __restrict__ b2,
    float* __restrict__ pooled, int Nn)
{
    int lane = threadIdx.x & 63;
    int h = lane >> 4, j = lane & 15;
    int waveId = blockIdx.x * (blockDim.x >> 6) + (threadIdx.x >> 6);
    int nWaves = gridDim.x * (blockDim.x >> 6);

    // R2 live columns in registers: c0=col j, c1=col j+16 (rk), c2=col 32+j (rv0)
    float c0[16], c1[16], c2[16];
#pragma unroll
    for (int r = 0; r < 16; ++r) {
        const float* row = R2 + (size_t)(h * 16 + r) * 64;
        c0[r] = row[j]; c1[r] = row[j + 16]; c2[r] = row[32 + j];
    }
    float r1l = R1[lane], b1l = b1[lane];
    float bk0 = b2[h * 64 + j];
    float bk1 = b2[h * 64 + j + 16];
    float bv  = b2[h * 64 + 32 + j];
    const float rs = 0.17677669529663687f; // 1/sqrt(32)

    for (int n = waveId; n < Nn; n += nWaves) {
        int start = offs[n], cnt = deg[n];
        if (cnt == 0) continue;
        float q0 = QKV[(size_t)n * 320 + h * 32 + j];
        float q1 = QKV[(size_t)n * 320 + h * 32 + j + 16];
        float m = -3.0e38f, l = 0.f, acc = 0.f;
        for (int e = start; e < start + cnt; ++e) {
            int   src = csr_src[e];
            float d   = csr_d[e];
            float x   = fmaf(d, r1l, b1l);
            float rhv = x / (1.f + __expf(-x));       // silu, lane=(h,r)
            float rk0 = bk0, rk1 = bk1, rv = bv;
#pragma unroll
            for (int r = 0; r < 16; ++r) {
                float rr = __shfl(rhv, (h << 4) + r);
                rk0 = fmaf(rr, c0[r], rk0);
                rk1 = fmaf(rr, c1[r], rk1);
                rv  = fmaf(rr, c2[r], rv);
            }
            const float* base = QKV + (size_t)src * 320;
            float k0 = base[128 + h * 32 + j];
            float k1 = base[128 + h * 32 + j + 16];
            float v0 = base[256 + h * 16 + j];
            float part = q0 * k0 * rk0 + q1 * k1 * rk1;
            part += __shfl_xor(part, 1);
            part += __shfl_xor(part, 2);
            part += __shfl_xor(part, 4);
            part += __shfl_xor(part, 8);
            float sc  = part * rs;
            float mn  = fmaxf(m, sc);
            float sca = __expf(m - mn);
            float ex  = __expf(sc - mn);
            l   = fmaf(l, sca, ex);
            acc = acc * sca + ex * v0 * rv;
            m = mn;
        }
        float o = acc / (l + 1e-9f);
        atomicAdd(&pooled[(size_t)batch[n] * 64 + lane], o);
    }
}

// ---------------------------------------------------------------------------
// Kernel 6: out[b][o] = sum_i pooled[b][i] * Wproj[i][o]
// ---------------------------------------------------------------------------
__global__ __launch_bounds__(256) void final_proj(
    const float* __restrict__ pooled, const float* __restrict__ Wproj,
    float* __restrict__ out, int total)
{
    int idx = blockIdx.x * 256 + threadIdx.x;
    if (idx >= total) return;
    int b = idx >> 6, o = idx & 63;
    float acc = 0.f;
#pragma unroll
    for (int i = 0; i < 64; ++i) acc += pooled[b * 64 + i] * Wproj[i * 64 + o];
    out[idx] = acc;
}

extern "C" void kernel_launch(void* const* d_in, const int* in_sizes, int n_in,
                              void* d_out, int out_size, void* d_ws, size_t ws_size,
                              hipStream_t stream)
{
    const float* pos   = (const float*)d_in[0];
    const float* nf    = (const float*)d_in[1];
    const int*   ei    = (const int*)d_in[2];
    const int*   batch = (const int*)d_in[3];
    const float* W_emb = (const float*)d_in[4];
    const float* b_emb = (const float*)d_in[5];
    const float* Wq    = (const float*)d_in[6];
    const float* Wk    = (const float*)d_in[7];
    const float* Wv0   = (const float*)d_in[8];
    const float* R1    = (const float*)d_in[10];
    const float* b1    = (const float*)d_in[11];
    const float* R2    = (const float*)d_in[12];
    const float* b2    = (const float*)d_in[13];
    const float* Wproj = (const float*)d_in[14];
    float* out = (float*)d_out;

    long Nn = in_sizes[0] / 3;
    long Ee = in_sizes[2] / 2;
    int  Bb = out_size / 64;

    float* ws = (float*)d_ws;
    size_t WCOMB = 0;
    size_t BCOMB = WCOMB + 32 * 320;
    size_t QKV_O = BCOMB + 320;
    size_t DEG   = QKV_O + (size_t)Nn * 320;
    size_t POOL  = DEG + (size_t)Nn;            // contiguous with DEG for one memset
    size_t OFFS  = POOL + (size_t)Bb * 64;
    size_t CURS  = OFFS + (size_t)Nn;
    size_t CSRS  = CURS + (size_t)Nn;
    size_t CSRD  = CSRS + (size_t)Ee;

    // zero deg + pooled (contiguous); offs/cursor/csr are fully written before read
    hipMemsetAsync(ws + DEG, 0, ((size_t)Nn + (size_t)Bb * 64) * sizeof(float), stream);

    fold_weights<<<idiv_up(33 * 320, 256), 256, 0, stream>>>(
        W_emb, b_emb, Wq, Wk, Wv0, ws + WCOMB, ws + BCOMB);

    node_qkv<<<idiv_up(Nn, 256) * 10, 256, 0, stream>>>(
        nf, ws + WCOMB, ws + BCOMB, ws + QKV_O, (int)Nn);

    count_deg<<<idiv_up(Ee, 256), 256, 0, stream>>>(
        ei, (int*)(ws + DEG), (int)Ee);

    scan_deg<<<1, 1024, 0, stream>>>(
        (const int*)(ws + DEG), (int*)(ws + OFFS), (int*)(ws + CURS), (int)Nn);

    scatter_edges<<<idiv_up(Ee, 256), 256, 0, stream>>>(
        pos, ei, (int*)(ws + CURS), (int*)(ws + CSRS), ws + CSRD, (int)Ee);

    node_attn<<<1024, 256, 0, stream>>>(
        ws + QKV_O, (const int*)(ws + CSRS), ws + CSRD,
        (const int*)(ws + OFFS), (const int*)(ws + DEG), batch,
        R1, b1, R2, b2, ws + POOL, (int)Nn);

    final_proj<<<idiv_up(out_size, 256), 256, 0, stream>>>(
        ws + POOL, Wproj, out, out_size);
}